// Round 6
// baseline (690.640 us; speedup 1.0000x reference)
//
#include <hip/hip_runtime.h>

// RNN_arch_2: 16-step RNN, B=16384, D_IN=64, D_H=256, D_MID=64, D_OUT=4.
// R6: row-partition, ZERO-BARRIER design. The recurrence is row-independent,
// so each wave owns 16 batch rows for all 16 steps. Transposed orientation
// (pre^T = Wcat @ [x|h]^T, M=features, N=batch): C-layout col and B-layout n
// are both batch=l16, so h never leaves the lane column — C->B conversion is
// a cross-quad ds_bpermute shuffle, no LDS round-trip, no syncthreads.
// Wh in LDS fragment-major (128 KB, conflict-free b128 reads), Wi/Wo/Wf in
// registers. 256 blocks x 256 thr, 1 block/CU, 1 wave/SIMD, 512-reg budget.

typedef _Float16 half8 __attribute__((ext_vector_type(8)));
typedef float floatx4 __attribute__((ext_vector_type(4)));
typedef int int4v __attribute__((ext_vector_type(4)));

#define T_STEPS 16
#define BATCH   16384

#define MFMA(a,b,c) __builtin_amdgcn_mfma_f32_16x16x32_f16((a),(b),(c),0,0,0)

__device__ inline float fast_tanh(float x) {
    float t = __builtin_amdgcn_exp2f(x * 2.8853900817779268f);
    return 1.0f - 2.0f * __builtin_amdgcn_rcpf(t + 1.0f);
}

__device__ inline half8 cvt8pair(float4 a, float4 b) {
    half8 h;
    h[0] = (_Float16)a.x; h[1] = (_Float16)a.y; h[2] = (_Float16)a.z; h[3] = (_Float16)a.w;
    h[4] = (_Float16)b.x; h[5] = (_Float16)b.y; h[6] = (_Float16)b.z; h[7] = (_Float16)b.w;
    return h;
}

__device__ inline int pack2h(float a, float b) {
    _Float16 ha = (_Float16)a, hb = (_Float16)b;
    unsigned short ua = __builtin_bit_cast(unsigned short, ha);
    unsigned short ub = __builtin_bit_cast(unsigned short, hb);
    return (int)ua | ((int)ub << 16);
}

// C-layout (2 packed-f16 b32 per M-tile) -> B-frag for k-tile built from
// tiles {L=2ks, H=2ks+1}. Target lane (l16,q) j-th half: feature 32ks+8q+j,
// src tile 2ks+(q>>1), src quad 2(q&1)+(j>>2), src reg j&3.
__device__ inline half8 gatherB(int pkL0, int pkL1, int pkH0, int pkH1,
                                int addr_lo, int addr_hi, bool hiM) {
    int a0 = __builtin_amdgcn_ds_bpermute(addr_lo, pkL0);
    int a1 = __builtin_amdgcn_ds_bpermute(addr_lo, pkL1);
    int a2 = __builtin_amdgcn_ds_bpermute(addr_hi, pkL0);
    int a3 = __builtin_amdgcn_ds_bpermute(addr_hi, pkL1);
    int b0 = __builtin_amdgcn_ds_bpermute(addr_lo, pkH0);
    int b1 = __builtin_amdgcn_ds_bpermute(addr_lo, pkH1);
    int b2 = __builtin_amdgcn_ds_bpermute(addr_hi, pkH0);
    int b3 = __builtin_amdgcn_ds_bpermute(addr_hi, pkH1);
    int4v v = { hiM ? b0 : a0, hiM ? b1 : a1, hiM ? b2 : a2, hiM ? b3 : a3 };
    return __builtin_bit_cast(half8, v);
}

__global__ __launch_bounds__(256, 1) void rnn_kernel(
    const float* __restrict__ x,   const float* __restrict__ hc1,
    const float* __restrict__ Wi,  const float* __restrict__ bi,
    const float* __restrict__ Wh,  const float* __restrict__ bh,
    const float* __restrict__ Wo,  const float* __restrict__ bo,
    const float* __restrict__ Wf,  const float* __restrict__ bfc,
    float* __restrict__ out)
{
    // Wh fragment-major: chunk c = M*8+ks (M=0..15 feature tile, ks=0..7
    // k-tile); within chunk, lane-order 16B frags -> conflict-free b128.
    __shared__ _Float16 wh_lds[65536];   // 131072 B
    __shared__ float bpre_l[256];
    __shared__ float bo_l[64];

    const int tid  = threadIdx.x;
    const int w    = tid >> 6;
    const int lane = tid & 63;
    const int l16  = lane & 15;
    const int quad = lane >> 4;
    const int myrow = blockIdx.x * 64 + w * 16 + l16;   // this lane's batch row

    // biases -> LDS (read back as broadcast floatx4 acc-init)
    bpre_l[tid] = bi[tid] + bh[tid];
    if (tid < 64) bo_l[tid] = bo[tid];

    // stage Wh (fp32 global, L2/L3-hot) -> LDS f16 fragment-major
    #pragma unroll
    for (int i = 0; i < 32; ++i) {
        int u = tid + 256 * i;            // half8 unit 0..8191
        int c = u >> 6, lu = u & 63;
        int row = (c >> 3) * 16 + (lu & 15);
        int col = (c & 7) * 32 + (lu >> 4) * 8;
        const float4* s = (const float4*)&Wh[row * 256 + col];
        *(half8*)&wh_lds[u * 8] = cvt8pair(s[0], s[1]);
    }

    // persistent register fragments (A-layout: m=l16, k=quad*8+j)
    half8 wiA[16][2];
    #pragma unroll
    for (int M = 0; M < 16; ++M)
        #pragma unroll
        for (int kt = 0; kt < 2; ++kt) {
            const float4* s = (const float4*)&Wi[(M * 16 + l16) * 64 + kt * 32 + quad * 8];
            wiA[M][kt] = cvt8pair(s[0], s[1]);
        }
    half8 woA[4][8];
    #pragma unroll
    for (int M2 = 0; M2 < 4; ++M2)
        #pragma unroll
        for (int ks = 0; ks < 8; ++ks) {
            const float4* s = (const float4*)&Wo[(M2 * 16 + l16) * 256 + ks * 32 + quad * 8];
            woA[M2][ks] = cvt8pair(s[0], s[1]);
        }
    half8 wfA[2];
    #pragma unroll
    for (int kt = 0; kt < 2; ++kt) {
        half8 z = (half8){0,0,0,0,0,0,0,0};
        if (l16 < 4) {
            const float4* s = (const float4*)&Wf[l16 * 64 + kt * 32 + quad * 8];
            z = cvt8pair(s[0], s[1]);
        }
        wfA[kt] = z;
    }
    const float4 bfcv = *(const float4*)bfc;

    // h state in registers, B-layout: hB[ks] = h[myrow][ks*32+quad*8 ..+8]
    half8 hB[8];
    #pragma unroll
    for (int ks = 0; ks < 8; ++ks) {
        const float4* s = (const float4*)&hc1[(size_t)myrow * 256 + ks * 32 + quad * 8];
        hB[ks] = cvt8pair(s[0], s[1]);
    }
    // x(0) B-frags
    half8 xB[2];
    {
        const float* xp = x + (size_t)myrow * 64 + quad * 8;
        xB[0] = cvt8pair(((const float4*)xp)[0], ((const float4*)xp)[1]);
        xB[1] = cvt8pair(((const float4*)(xp + 32))[0], ((const float4*)(xp + 32))[1]);
    }

    const int addr_lo = (l16 + 32 * (quad & 1)) * 4;   // src lane quad 2(q&1)
    const int addr_hi = addr_lo + 64;                  // src lane quad 2(q&1)+1
    const bool hiM = quad >= 2;

    __syncthreads();   // the ONLY barrier: wh_lds/bias visible

    for (int t = 0; t < T_STEPS; ++t) {
        // prefetch x(t+1) raw fp32 (latency hidden under the GEMM)
        float4 xr0, xr1, xr2, xr3;
        if (t < T_STEPS - 1) {
            const float* xp = x + ((size_t)(t + 1) * BATCH + myrow) * 64 + quad * 8;
            xr0 = ((const float4*)xp)[0];        xr1 = ((const float4*)xp)[1];
            xr2 = ((const float4*)(xp + 32))[0]; xr3 = ((const float4*)(xp + 32))[1];
        }

        // pre^T = Wcat @ [x|h]^T : 16 M-tiles, processed in pairs for ILP
        int pk[16][2];
        #pragma unroll
        for (int Mp = 0; Mp < 8; ++Mp) {
            const int M0 = 2 * Mp, M1 = M0 + 1;
            floatx4 acc0 = *(const floatx4*)&bpre_l[M0 * 16 + quad * 4];
            floatx4 acc1 = *(const floatx4*)&bpre_l[M1 * 16 + quad * 4];
            acc0 = MFMA(wiA[M0][0], xB[0], acc0);
            acc1 = MFMA(wiA[M1][0], xB[0], acc1);
            acc0 = MFMA(wiA[M0][1], xB[1], acc0);
            acc1 = MFMA(wiA[M1][1], xB[1], acc1);
            #pragma unroll
            for (int ks = 0; ks < 8; ++ks) {
                half8 a0 = *(const half8*)&wh_lds[((M0 * 8 + ks) * 64 + lane) * 8];
                half8 a1 = *(const half8*)&wh_lds[((M1 * 8 + ks) * 64 + lane) * 8];
                acc0 = MFMA(a0, hB[ks], acc0);
                acc1 = MFMA(a1, hB[ks], acc1);
            }
            pk[M0][0] = pack2h(fast_tanh(acc0[0] ), fast_tanh(acc0[1]));
            pk[M0][1] = pack2h(fast_tanh(acc0[2]), fast_tanh(acc0[3]));
            pk[M1][0] = pack2h(fast_tanh(acc1[0]), fast_tanh(acc1[1]));
            pk[M1][1] = pack2h(fast_tanh(acc1[2]), fast_tanh(acc1[3]));
        }
        // h_{t+1}: C-layout -> B-layout via cross-quad bpermute
        #pragma unroll
        for (int ks = 0; ks < 8; ++ks)
            hB[ks] = gatherB(pk[2*ks][0], pk[2*ks][1], pk[2*ks+1][0], pk[2*ks+1][1],
                             addr_lo, addr_hi, hiM);

        // mid^T = Wo @ h_{t+1}^T (4 M-tiles), then C->B, then fc
        int pkm[4][2];
        #pragma unroll
        for (int M2 = 0; M2 < 4; ++M2) {
            floatx4 m = *(const floatx4*)&bo_l[M2 * 16 + quad * 4];
            #pragma unroll
            for (int ks = 0; ks < 8; ++ks)
                m = MFMA(woA[M2][ks], hB[ks], m);
            pkm[M2][0] = pack2h(fast_tanh(m[0]), fast_tanh(m[1]));
            pkm[M2][1] = pack2h(fast_tanh(m[2]), fast_tanh(m[3]));
        }
        half8 mB0 = gatherB(pkm[0][0], pkm[0][1], pkm[1][0], pkm[1][1],
                            addr_lo, addr_hi, hiM);
        half8 mB1 = gatherB(pkm[2][0], pkm[2][1], pkm[3][0], pkm[3][1],
                            addr_lo, addr_hi, hiM);
        floatx4 f = {0.f, 0.f, 0.f, 0.f};
        f = MFMA(wfA[0], mB0, f);
        f = MFMA(wfA[1], mB1, f);
        if (quad == 0) {   // C row = out-feature 0..3 lives in quad 0
            float4 o;
            o.x = f[0] + bfcv.x; o.y = f[1] + bfcv.y;
            o.z = f[2] + bfcv.z; o.w = f[3] + bfcv.w;
            *(float4*)&out[((size_t)t * BATCH + myrow) * 4] = o;
        }

        if (t < T_STEPS - 1) {
            xB[0] = cvt8pair(xr0, xr1);
            xB[1] = cvt8pair(xr2, xr3);
        }
    }

    // h_final (fp32): hB is already h_16 in [row][feature] lane order
    {
        float* hf = out + (size_t)T_STEPS * BATCH * 4 + (size_t)myrow * 256;
        #pragma unroll
        for (int ks = 0; ks < 8; ++ks) {
            float4 o0, o1;
            o0.x = (float)hB[ks][0]; o0.y = (float)hB[ks][1];
            o0.z = (float)hB[ks][2]; o0.w = (float)hB[ks][3];
            o1.x = (float)hB[ks][4]; o1.y = (float)hB[ks][5];
            o1.z = (float)hB[ks][6]; o1.w = (float)hB[ks][7];
            *(float4*)&hf[ks * 32 + quad * 8]     = o0;
            *(float4*)&hf[ks * 32 + quad * 8 + 4] = o1;
        }
    }
}

extern "C" void kernel_launch(void* const* d_in, const int* in_sizes, int n_in,
                              void* d_out, int out_size, void* d_ws, size_t ws_size,
                              hipStream_t stream) {
    const float* x   = (const float*)d_in[0];
    const float* hc1 = (const float*)d_in[1];
    const float* Wi  = (const float*)d_in[2];
    const float* bi  = (const float*)d_in[3];
    const float* Wh  = (const float*)d_in[4];
    const float* bh  = (const float*)d_in[5];
    const float* Wo  = (const float*)d_in[6];
    const float* bo  = (const float*)d_in[7];
    const float* Wf  = (const float*)d_in[8];
    const float* bf  = (const float*)d_in[9];

    rnn_kernel<<<256, 256, 0, stream>>>(x, hc1, Wi, bi, Wh, bh, Wo, bo, Wf, bf,
                                        (float*)d_out);
}